// Round 1
// baseline (1188.058 us; speedup 1.0000x reference)
//
#include <hip/hip_runtime.h>
#include <math.h>

#define TSIZE (1u << 19)
#define NTHREADS 256

struct LevelParams {
    float scale[16];
    unsigned res[16];
    unsigned dense_mask;
};

// LDS layout (float offsets)
#define OFF_W1   0      // 32x64 = 2048
#define OFF_W2   2048   // 64x16 = 1024
#define OFF_WA1  3072   // 16x32 = 512
#define OFF_WA2  3584   // 32
#define OFF_WU1  3616   // 16x32 = 512
#define OFF_WU2  4128   // 32
#define OFF_WR1  4160   // 32x64 = 2048
#define OFF_WR2  6208   // 64x64 = 4096
#define OFF_WR3  10304  // 64x3 = 192
#define SMEM_TOTAL 10496

__global__ __launch_bounds__(NTHREADS, 2)
void ngp_fused(const float* __restrict__ x, const float* __restrict__ dirs,
               const float* __restrict__ table,
               const float* __restrict__ w1, const float* __restrict__ w2,
               const float* __restrict__ wa1, const float* __restrict__ wa2,
               const float* __restrict__ wu1, const float* __restrict__ wu2,
               const float* __restrict__ wr1, const float* __restrict__ wr2,
               const float* __restrict__ wr3,
               float* __restrict__ out, int N, LevelParams lp)
{
    __shared__ float smem[SMEM_TOTAL];
    const int tid = threadIdx.x;
    for (int t = tid; t < 2048; t += NTHREADS) smem[OFF_W1 + t] = w1[t];
    for (int t = tid; t < 1024; t += NTHREADS) smem[OFF_W2 + t] = w2[t];
    for (int t = tid; t < 512;  t += NTHREADS) smem[OFF_WA1 + t] = wa1[t];
    for (int t = tid; t < 32;   t += NTHREADS) smem[OFF_WA2 + t] = wa2[t];
    for (int t = tid; t < 512;  t += NTHREADS) smem[OFF_WU1 + t] = wu1[t];
    for (int t = tid; t < 32;   t += NTHREADS) smem[OFF_WU2 + t] = wu2[t];
    for (int t = tid; t < 2048; t += NTHREADS) smem[OFF_WR1 + t] = wr1[t];
    for (int t = tid; t < 4096; t += NTHREADS) smem[OFF_WR2 + t] = wr2[t];
    for (int t = tid; t < 192;  t += NTHREADS) smem[OFF_WR3 + t] = wr3[t];
    __syncthreads();

    const int i = blockIdx.x * NTHREADS + tid;
    if (i >= N) return;

    const float x0 = (x[3 * i + 0] + 1.0f) * 0.5f;
    const float y0 = (x[3 * i + 1] + 1.0f) * 0.5f;
    const float z0 = (x[3 * i + 2] + 1.0f) * 0.5f;

    const float2* __restrict__ tab2 = reinterpret_cast<const float2*>(table);

    // ---------------- grid encode ----------------
    float enc[32];
    #pragma unroll
    for (int l = 0; l < 16; l++) {
        const float s = lp.scale[l];
        const unsigned res = lp.res[l];
        const bool dense = (lp.dense_mask >> l) & 1u;
        const float posx = x0 * s + 0.5f;
        const float posy = y0 * s + 0.5f;
        const float posz = z0 * s + 0.5f;
        const float pgx = floorf(posx), pgy = floorf(posy), pgz = floorf(posz);
        const float fx = posx - pgx, fy = posy - pgy, fz = posz - pgz;
        const unsigned ux = (unsigned)pgx, uy = (unsigned)pgy, uz = (unsigned)pgz;
        const unsigned base = (unsigned)l * TSIZE;
        float f0 = 0.f, f1 = 0.f;
        #pragma unroll
        for (int c = 0; c < 8; c++) {
            const unsigned bi = (c >> 2) & 1u, bj = (c >> 1) & 1u, bk = c & 1u;
            const unsigned cx = ux + bi, cy = uy + bj, cz = uz + bk;
            unsigned idx;
            if (dense) idx = cx + cy * res + cz * res * res;
            else       idx = (cx * 1u ^ cy * 2654435761u ^ cz * 805459861u) & (TSIZE - 1u);
            const float w = (bi ? fx : 1.f - fx) * (bj ? fy : 1.f - fy) * (bk ? fz : 1.f - fz);
            const float2 f = tab2[base + idx];
            f0 += w * f.x;
            f1 += w * f.y;
        }
        enc[2 * l]     = f0;
        enc[2 * l + 1] = f1;
    }

    // ---------------- layer 1: a1 = relu(enc @ w1)  (32 -> 64) ----------------
    float a1[64];
    #pragma unroll
    for (int j = 0; j < 64; j++) a1[j] = 0.f;
    #pragma unroll
    for (int k = 0; k < 32; k++) {
        const float e = enc[k];
        const float4* row = reinterpret_cast<const float4*>(&smem[OFF_W1 + k * 64]);
        #pragma unroll
        for (int j = 0; j < 16; j++) {
            const float4 w4 = row[j];
            a1[4 * j + 0] += e * w4.x;
            a1[4 * j + 1] += e * w4.y;
            a1[4 * j + 2] += e * w4.z;
            a1[4 * j + 3] += e * w4.w;
        }
    }
    #pragma unroll
    for (int j = 0; j < 64; j++) a1[j] = fmaxf(a1[j], 0.f);

    // ---------------- layer 2: h = a1 @ w2  (64 -> 16) ----------------
    float h[16];
    #pragma unroll
    for (int j = 0; j < 16; j++) h[j] = 0.f;
    #pragma unroll
    for (int k = 0; k < 64; k++) {
        const float a = a1[k];
        const float4* row = reinterpret_cast<const float4*>(&smem[OFF_W2 + k * 16]);
        #pragma unroll
        for (int j = 0; j < 4; j++) {
            const float4 w4 = row[j];
            h[4 * j + 0] += a * w4.x;
            h[4 * j + 1] += a * w4.y;
            h[4 * j + 2] += a * w4.z;
            h[4 * j + 3] += a * w4.w;
        }
    }

    // ---------------- sigma: exp(relu(h @ wa1) @ wa2) ----------------
    float sigma;
    {
        float t32[32];
        #pragma unroll
        for (int j = 0; j < 32; j++) t32[j] = 0.f;
        #pragma unroll
        for (int k = 0; k < 16; k++) {
            const float a = h[k];
            const float4* row = reinterpret_cast<const float4*>(&smem[OFF_WA1 + k * 32]);
            #pragma unroll
            for (int j = 0; j < 8; j++) {
                const float4 w4 = row[j];
                t32[4 * j + 0] += a * w4.x;
                t32[4 * j + 1] += a * w4.y;
                t32[4 * j + 2] += a * w4.z;
                t32[4 * j + 3] += a * w4.w;
            }
        }
        float acc = 0.f;
        #pragma unroll
        for (int j = 0; j < 32; j++) acc += fmaxf(t32[j], 0.f) * smem[OFF_WA2 + j];
        sigma = expf(acc);
    }

    // ---------------- uncert: exp((h @ wu1) @ wu2)  (no relu) ----------------
    float uncert;
    {
        float u32[32];
        #pragma unroll
        for (int j = 0; j < 32; j++) u32[j] = 0.f;
        #pragma unroll
        for (int k = 0; k < 16; k++) {
            const float a = h[k];
            const float4* row = reinterpret_cast<const float4*>(&smem[OFF_WU1 + k * 32]);
            #pragma unroll
            for (int j = 0; j < 8; j++) {
                const float4 w4 = row[j];
                u32[4 * j + 0] += a * w4.x;
                u32[4 * j + 1] += a * w4.y;
                u32[4 * j + 2] += a * w4.z;
                u32[4 * j + 3] += a * w4.w;
            }
        }
        float acc = 0.f;
        #pragma unroll
        for (int j = 0; j < 32; j++) acc += u32[j] * smem[OFF_WU2 + j];
        uncert = expf(acc);
    }

    // ---------------- SH degree 4 of v = ((d+1)*0.5)*2 - 1 ----------------
    float in32[32];
    {
        const float dx = dirs[3 * i + 0], dy = dirs[3 * i + 1], dz = dirs[3 * i + 2];
        const float vx = (dx + 1.0f) * 0.5f * 2.0f - 1.0f;
        const float vy = (dy + 1.0f) * 0.5f * 2.0f - 1.0f;
        const float vz = (dz + 1.0f) * 0.5f * 2.0f - 1.0f;
        const float x2 = vx * vx, y2 = vy * vy, z2 = vz * vz;
        const float xy = vx * vy, yz = vy * vz, xz = vx * vz;
        in32[0]  = 0.28209479177387814f;
        in32[1]  = -0.48860251190291987f * vy;
        in32[2]  = 0.48860251190291987f * vz;
        in32[3]  = -0.48860251190291987f * vx;
        in32[4]  = 1.0925484305920792f * xy;
        in32[5]  = -1.0925484305920792f * yz;
        in32[6]  = 0.94617469575756f * z2 - 0.31539156525252f;
        in32[7]  = -1.0925484305920792f * xz;
        in32[8]  = 0.5462742152960396f * (x2 - y2);
        in32[9]  = 0.5900435899266435f * vy * (-3.0f * x2 + y2);
        in32[10] = 2.890611442640554f * xy * vz;
        in32[11] = 0.4570457994644657f * vy * (1.0f - 5.0f * z2);
        in32[12] = 0.3731763325901154f * vz * (5.0f * z2 - 3.0f);
        in32[13] = 0.4570457994644657f * vx * (1.0f - 5.0f * z2);
        in32[14] = 1.445305721320277f * vz * (x2 - y2);
        in32[15] = 0.5900435899266435f * vx * (-x2 + 3.0f * y2);
        #pragma unroll
        for (int j = 0; j < 16; j++) in32[16 + j] = h[j];
    }

    // ---------------- z1 = relu(in32 @ wr1)  (32 -> 64) ----------------
    float z1[64];
    #pragma unroll
    for (int j = 0; j < 64; j++) z1[j] = 0.f;
    #pragma unroll
    for (int k = 0; k < 32; k++) {
        const float a = in32[k];
        const float4* row = reinterpret_cast<const float4*>(&smem[OFF_WR1 + k * 64]);
        #pragma unroll
        for (int j = 0; j < 16; j++) {
            const float4 w4 = row[j];
            z1[4 * j + 0] += a * w4.x;
            z1[4 * j + 1] += a * w4.y;
            z1[4 * j + 2] += a * w4.z;
            z1[4 * j + 3] += a * w4.w;
        }
    }
    #pragma unroll
    for (int j = 0; j < 64; j++) z1[j] = fmaxf(z1[j], 0.f);

    // ---------------- z2 = relu(z1 @ wr2)  (64 -> 64) ----------------
    float z2[64];
    #pragma unroll
    for (int j = 0; j < 64; j++) z2[j] = 0.f;
    #pragma unroll
    for (int k = 0; k < 64; k++) {
        const float a = z1[k];
        const float4* row = reinterpret_cast<const float4*>(&smem[OFF_WR2 + k * 64]);
        #pragma unroll
        for (int j = 0; j < 16; j++) {
            const float4 w4 = row[j];
            z2[4 * j + 0] += a * w4.x;
            z2[4 * j + 1] += a * w4.y;
            z2[4 * j + 2] += a * w4.z;
            z2[4 * j + 3] += a * w4.w;
        }
    }
    #pragma unroll
    for (int j = 0; j < 64; j++) z2[j] = fmaxf(z2[j], 0.f);

    // ---------------- rgb = sigmoid(z2 @ wr3)  (64 -> 3) ----------------
    float r0 = 0.f, r1 = 0.f, r2 = 0.f;
    #pragma unroll
    for (int k = 0; k < 64; k++) {
        const float a = z2[k];
        r0 += a * smem[OFF_WR3 + k * 3 + 0];
        r1 += a * smem[OFF_WR3 + k * 3 + 1];
        r2 += a * smem[OFF_WR3 + k * 3 + 2];
    }
    r0 = 1.0f / (1.0f + expf(-r0));
    r1 = 1.0f / (1.0f + expf(-r1));
    r2 = 1.0f / (1.0f + expf(-r2));

    out[i] = sigma;
    out[N + 3 * i + 0] = r0;
    out[N + 3 * i + 1] = r1;
    out[N + 3 * i + 2] = r2;
    out[4 * N + i] = uncert;
}

extern "C" void kernel_launch(void* const* d_in, const int* in_sizes, int n_in,
                              void* d_out, int out_size, void* d_ws, size_t ws_size,
                              hipStream_t stream) {
    const float* x     = (const float*)d_in[0];
    const float* dirs  = (const float*)d_in[1];
    const float* table = (const float*)d_in[2];
    const float* w1    = (const float*)d_in[3];
    const float* w2    = (const float*)d_in[4];
    const float* wa1   = (const float*)d_in[5];
    const float* wa2   = (const float*)d_in[6];
    const float* wu1   = (const float*)d_in[7];
    const float* wu2   = (const float*)d_in[8];
    const float* wr1   = (const float*)d_in[9];
    const float* wr2   = (const float*)d_in[10];
    const float* wr3   = (const float*)d_in[11];
    float* out = (float*)d_out;

    const int N = in_sizes[0] / 3;

    LevelParams lp;
    const double b = exp(log(2048.0 / 16.0) / 15.0);
    unsigned dm = 0;
    for (int l = 0; l < 16; l++) {
        const double s = 16.0 * pow(b, (double)l) - 1.0;
        lp.scale[l] = (float)s;
        const int r = (int)ceil(s) + 1;
        lp.res[l] = (unsigned)r;
        if ((long long)r * r * r <= (long long)TSIZE) dm |= (1u << l);
    }
    lp.dense_mask = dm;

    const int blocks = (N + NTHREADS - 1) / NTHREADS;
    hipLaunchKernelGGL(ngp_fused, dim3(blocks), dim3(NTHREADS), 0, stream,
                       x, dirs, table, w1, w2, wa1, wa2, wu1, wu2, wr1, wr2, wr3,
                       out, N, lp);
}